// Round 1
// baseline (942.711 us; speedup 1.0000x reference)
//
#include <hip/hip_runtime.h>
#include <math.h>

#define H 2048
#define B 1024
#define NB 12

// ws layout (floats):
//   [0,    H)   : x  (current LSTM input vector)
//   [H,   2H)   : h
//   [2H,  3H)   : c
//   [3H,  7H)   : gates (4H = 8192)
//   [7H]        : idx (int stored in float slot)

__global__ __launch_bounds__(256) void zero_c_kernel(float* __restrict__ cv) {
    int j = blockIdx.x * 256 + threadIdx.x;
    if (j < H) cv[j] = 0.f;
}

// step 0: x = h = 0  =>  gates = b_ih + b_hh
__global__ __launch_bounds__(256) void bias_gates_kernel(
    const float* __restrict__ bih, const float* __restrict__ bhh,
    float* __restrict__ gates) {
    int j = blockIdx.x * 256 + threadIdx.x;
    if (j < 4 * H) gates[j] = bih[j] + bhh[j];
}

// gates[r] = dot(W_ih[r], x) + dot(W_hh[r], h) + b_ih[r] + b_hh[r]
// one wave (64 lanes) per output row; 2048 blocks x 256 threads = 8192 rows
__global__ __launch_bounds__(256) void gates_kernel(
    const float* __restrict__ Wih, const float* __restrict__ Whh,
    const float* __restrict__ bih, const float* __restrict__ bhh,
    const float* __restrict__ x, const float* __restrict__ h,
    float* __restrict__ gates) {
    const int wave = threadIdx.x >> 6;
    const int lane = threadIdx.x & 63;
    const int row = blockIdx.x * 4 + wave;  // < 8192 always

    const float4* __restrict__ Wi4 = (const float4*)(Wih + (size_t)row * H);
    const float4* __restrict__ Wh4 = (const float4*)(Whh + (size_t)row * H);
    const float4* __restrict__ x4 = (const float4*)x;
    const float4* __restrict__ h4 = (const float4*)h;

    float acc = 0.f;
#pragma unroll
    for (int k = 0; k < H / 256; ++k) {  // 8 iterations
        int j = k * 64 + lane;
        float4 w = Wi4[j];
        float4 v = x4[j];
        acc += w.x * v.x + w.y * v.y + w.z * v.z + w.w * v.w;
    }
#pragma unroll
    for (int k = 0; k < H / 256; ++k) {
        int j = k * 64 + lane;
        float4 w = Wh4[j];
        float4 v = h4[j];
        acc += w.x * v.x + w.y * v.y + w.z * v.z + w.w * v.w;
    }
    // 64-lane wave reduction
    for (int off = 32; off > 0; off >>= 1) acc += __shfl_down(acc, off, 64);
    if (lane == 0) gates[row] = acc + bih[row] + bhh[row];
}

// single-block: h,c update from gates; logits = h @ dec[0:nclass].T; argmax;
// gather next x = enc[idx] (if enc != nullptr)
__global__ __launch_bounds__(256) void update_kernel(
    const float* __restrict__ gates,
    float* __restrict__ xv, float* __restrict__ hv, float* __restrict__ cv,
    const float* __restrict__ dec, int nclass,
    const float* __restrict__ enc, int* __restrict__ idx_ptr) {
    const int t = threadIdx.x;
    __shared__ float red[256];
    __shared__ float logits[16];
    __shared__ int sidx;

    float hl[8];
#pragma unroll
    for (int k = 0; k < 8; ++k) {
        int j = k * 256 + t;
        float ig = gates[j];
        float fg = gates[H + j];
        float gg = gates[2 * H + j];
        float og = gates[3 * H + j];
        float si = 1.f / (1.f + expf(-ig));
        float sf = 1.f / (1.f + expf(-fg));
        float so = 1.f / (1.f + expf(-og));
        float tg = tanhf(gg);
        float c2 = sf * cv[j] + si * tg;
        float h2 = so * tanhf(c2);
        cv[j] = c2;
        hv[j] = h2;
        hl[k] = h2;
    }
    __syncthreads();

    for (int cl = 0; cl < nclass; ++cl) {
        const float* dr = dec + (size_t)cl * H;
        float p = 0.f;
#pragma unroll
        for (int k = 0; k < 8; ++k) p += hl[k] * dr[k * 256 + t];
        red[t] = p;
        __syncthreads();
        for (int s = 128; s > 0; s >>= 1) {
            if (t < s) red[t] += red[t + s];
            __syncthreads();
        }
        if (t == 0) logits[cl] = red[0];
        __syncthreads();
    }

    if (t == 0) {
        float best = logits[0];
        int bi = 0;
        for (int cl = 1; cl < nclass; ++cl)
            if (logits[cl] > best) { best = logits[cl]; bi = cl; }
        sidx = bi;
        *idx_ptr = bi;
    }
    __syncthreads();

    if (enc != nullptr) {
        const float* er = enc + (size_t)sidx * H;
#pragma unroll
        for (int k = 0; k < 8; ++k) {
            int j = k * 256 + t;
            xv[j] = er[j];
        }
    }
}

// broadcast: out[0:B) = idx (as float); out[B : B+B*H) = h rows; then c rows
__global__ __launch_bounds__(256) void final_kernel(
    const float* __restrict__ hv, const float* __restrict__ cv,
    const int* __restrict__ idx_ptr, float* __restrict__ out) {
    const int tid = blockIdx.x * 256 + threadIdx.x;  // 0 .. B*H/4-1
    const int col = tid & (H / 4 - 1);
    const float4 h4 = ((const float4*)hv)[col];
    const float4 c4 = ((const float4*)cv)[col];
    ((float4*)(out + B))[tid] = h4;
    ((float4*)(out + B + (size_t)B * H))[tid] = c4;
    if (tid < B) out[tid] = (float)(*idx_ptr);
}

extern "C" void kernel_launch(void* const* d_in, const int* in_sizes, int n_in,
                              void* d_out, int out_size, void* d_ws, size_t ws_size,
                              hipStream_t stream) {
    const float* W_ih      = (const float*)d_in[1];
    const float* W_hh      = (const float*)d_in[2];
    const float* b_ih      = (const float*)d_in[3];
    const float* b_hh      = (const float*)d_in[4];
    const float* enc_act   = (const float*)d_in[5];  // (NB-1, 4, H)
    const float* enc_block = (const float*)d_in[6];  // (NB-1, NB-1, H)
    const float* dec_act   = (const float*)d_in[7];  // (NB, 4, H)
    const float* dec_block = (const float*)d_in[8];  // (NB-1, NB-1, H)

    float* ws = (float*)d_ws;
    float* xv    = ws;
    float* hv    = ws + H;
    float* cv    = ws + 2 * H;
    float* gates = ws + 3 * H;
    int*   idxp  = (int*)(ws + 7 * H);
    float* out = (float*)d_out;

    // block 0: x=h=c=0 -> gates = biases only
    zero_c_kernel<<<8, 256, 0, stream>>>(cv);
    bias_gates_kernel<<<32, 256, 0, stream>>>(b_ih, b_hh, gates);
    // activation decode 0, gather enc_act[0] for next step
    update_kernel<<<1, 256, 0, stream>>>(gates, xv, hv, cv,
                                         dec_act, 4, enc_act, idxp);

    for (int bid = 1; bid < NB; ++bid) {
        // forward_block: lstm(emb=enc_act[bid-1][idx]) then block decode (bid classes)
        gates_kernel<<<2048, 256, 0, stream>>>(W_ih, W_hh, b_ih, b_hh, xv, hv, gates);
        update_kernel<<<1, 256, 0, stream>>>(
            gates, xv, hv, cv,
            dec_block + (size_t)(bid - 1) * (NB - 1) * H, bid,
            enc_block + (size_t)(bid - 1) * (NB - 1) * H, idxp);

        // forward_activation: lstm(emb=enc_block[bid-1][idx]) then act decode (4 classes)
        gates_kernel<<<2048, 256, 0, stream>>>(W_ih, W_hh, b_ih, b_hh, xv, hv, gates);
        update_kernel<<<1, 256, 0, stream>>>(
            gates, xv, hv, cv,
            dec_act + (size_t)bid * 4 * H, 4,
            (bid < NB - 1) ? (enc_act + (size_t)bid * 4 * H) : nullptr, idxp);
    }

    final_kernel<<<2048, 256, 0, stream>>>(hv, cv, idxp, out);
}

// Round 2
// 778.880 us; speedup vs baseline: 1.2103x; 1.2103x over previous
//
#include <hip/hip_runtime.h>
#include <math.h>
#include <stdint.h>

#define H 2048
#define B 1024
#define NB 12

// bf16 weight stash in ws:
//   [0, 32MB)        : Wih_bf16 (8192 x 2048, row-major, packed 2/u32)
//   [32MB, 64MB)     : Whh_bf16
//   [64MB ...]       : fp32 state: x(H), h(H), c(H), gates(4H), idx(1)
#define WBF16_BYTES (8192ull * 2048ull * 2ull)        // per matrix: 32 MB
#define STATE_OFF_BYTES (2ull * WBF16_BYTES)          // 64 MB
#define STATE_FLOATS (7 * H + 1)

__global__ __launch_bounds__(256) void zero_c_kernel(float* __restrict__ cv) {
    int j = blockIdx.x * 256 + threadIdx.x;
    if (j < H) cv[j] = 0.f;
}

__global__ __launch_bounds__(256) void bias_gates_kernel(
    const float* __restrict__ bih, const float* __restrict__ bhh,
    float* __restrict__ gates) {
    int j = blockIdx.x * 256 + threadIdx.x;
    if (j < 4 * H) gates[j] = bih[j] + bhh[j];
}

// fp32 -> bf16 (RNE) pack: each thread converts 8 floats -> one uint4
// total uint4 per matrix = 8192*2048/8 = 2,097,152 -> 8192 blocks x 256
__device__ __forceinline__ uint32_t bf16rne(float f) {
    uint32_t u = __float_as_uint(f);
    return (u + 0x7fffu + ((u >> 16) & 1u)) >> 16;
}
__global__ __launch_bounds__(256) void convert_kernel(
    const float4* __restrict__ src, uint4* __restrict__ dst) {
    int i = blockIdx.x * 256 + threadIdx.x;  // uint4 index
    float4 a = src[2 * i];
    float4 b = src[2 * i + 1];
    uint4 o;
    o.x = bf16rne(a.x) | (bf16rne(a.y) << 16);
    o.y = bf16rne(a.z) | (bf16rne(a.w) << 16);
    o.z = bf16rne(b.x) | (bf16rne(b.y) << 16);
    o.w = bf16rne(b.z) | (bf16rne(b.w) << 16);
    dst[i] = o;
}

// bf16-weight matvec: one 64-lane wave per output row (8192 rows).
// Row = 2048 bf16 = 4096 B = 256 uint4; 4 iters x 64 lanes per matrix.
__global__ __launch_bounds__(256) void gates_bf16_kernel(
    const uint4* __restrict__ Wih, const uint4* __restrict__ Whh,
    const float* __restrict__ bih, const float* __restrict__ bhh,
    const float* __restrict__ x, const float* __restrict__ h,
    float* __restrict__ gates) {
    const int wave = threadIdx.x >> 6;
    const int lane = threadIdx.x & 63;
    const int row = blockIdx.x * 4 + wave;

    const uint4* __restrict__ Wi = Wih + (size_t)row * 256;
    const uint4* __restrict__ Wh = Whh + (size_t)row * 256;
    const float4* __restrict__ x4 = (const float4*)x;
    const float4* __restrict__ h4 = (const float4*)h;

    float acc = 0.f;
#pragma unroll
    for (int k = 0; k < 4; ++k) {
        int j = k * 64 + lane;
        uint4 w = Wi[j];
        float4 a = x4[2 * j];
        float4 b = x4[2 * j + 1];
        acc += __uint_as_float(w.x << 16) * a.x;
        acc += __uint_as_float(w.x & 0xffff0000u) * a.y;
        acc += __uint_as_float(w.y << 16) * a.z;
        acc += __uint_as_float(w.y & 0xffff0000u) * a.w;
        acc += __uint_as_float(w.z << 16) * b.x;
        acc += __uint_as_float(w.z & 0xffff0000u) * b.y;
        acc += __uint_as_float(w.w << 16) * b.z;
        acc += __uint_as_float(w.w & 0xffff0000u) * b.w;
    }
#pragma unroll
    for (int k = 0; k < 4; ++k) {
        int j = k * 64 + lane;
        uint4 w = Wh[j];
        float4 a = h4[2 * j];
        float4 b = h4[2 * j + 1];
        acc += __uint_as_float(w.x << 16) * a.x;
        acc += __uint_as_float(w.x & 0xffff0000u) * a.y;
        acc += __uint_as_float(w.y << 16) * a.z;
        acc += __uint_as_float(w.y & 0xffff0000u) * a.w;
        acc += __uint_as_float(w.z << 16) * b.x;
        acc += __uint_as_float(w.z & 0xffff0000u) * b.y;
        acc += __uint_as_float(w.w << 16) * b.z;
        acc += __uint_as_float(w.w & 0xffff0000u) * b.w;
    }
    for (int off = 32; off > 0; off >>= 1) acc += __shfl_down(acc, off, 64);
    if (lane == 0) gates[row] = acc + bih[row] + bhh[row];
}

// fp32 fallback matvec (used only if ws too small for bf16 stash)
__global__ __launch_bounds__(256) void gates_kernel(
    const float* __restrict__ Wih, const float* __restrict__ Whh,
    const float* __restrict__ bih, const float* __restrict__ bhh,
    const float* __restrict__ x, const float* __restrict__ h,
    float* __restrict__ gates) {
    const int wave = threadIdx.x >> 6;
    const int lane = threadIdx.x & 63;
    const int row = blockIdx.x * 4 + wave;

    const float4* __restrict__ Wi4 = (const float4*)(Wih + (size_t)row * H);
    const float4* __restrict__ Wh4 = (const float4*)(Whh + (size_t)row * H);
    const float4* __restrict__ x4 = (const float4*)x;
    const float4* __restrict__ h4 = (const float4*)h;

    float acc = 0.f;
#pragma unroll
    for (int k = 0; k < H / 256; ++k) {
        int j = k * 64 + lane;
        float4 w = Wi4[j];
        float4 v = x4[j];
        acc += w.x * v.x + w.y * v.y + w.z * v.z + w.w * v.w;
    }
#pragma unroll
    for (int k = 0; k < H / 256; ++k) {
        int j = k * 64 + lane;
        float4 w = Wh4[j];
        float4 v = h4[j];
        acc += w.x * v.x + w.y * v.y + w.z * v.z + w.w * v.w;
    }
    for (int off = 32; off > 0; off >>= 1) acc += __shfl_down(acc, off, 64);
    if (lane == 0) gates[row] = acc + bih[row] + bhh[row];
}

// single-block: h,c update; logits = h @ dec[0:nclass].T; argmax; gather x=enc[idx]
__global__ __launch_bounds__(256) void update_kernel(
    const float* __restrict__ gates,
    float* __restrict__ xv, float* __restrict__ hv, float* __restrict__ cv,
    const float* __restrict__ dec, int nclass,
    const float* __restrict__ enc, int* __restrict__ idx_ptr) {
    const int t = threadIdx.x;
    __shared__ float red[256];
    __shared__ float logits[16];
    __shared__ int sidx;

    float hl[8];
#pragma unroll
    for (int k = 0; k < 8; ++k) {
        int j = k * 256 + t;
        float ig = gates[j];
        float fg = gates[H + j];
        float gg = gates[2 * H + j];
        float og = gates[3 * H + j];
        float si = 1.f / (1.f + expf(-ig));
        float sf = 1.f / (1.f + expf(-fg));
        float so = 1.f / (1.f + expf(-og));
        float tg = tanhf(gg);
        float c2 = sf * cv[j] + si * tg;
        float h2 = so * tanhf(c2);
        cv[j] = c2;
        hv[j] = h2;
        hl[k] = h2;
    }
    __syncthreads();

    for (int cl = 0; cl < nclass; ++cl) {
        const float* dr = dec + (size_t)cl * H;
        float p = 0.f;
#pragma unroll
        for (int k = 0; k < 8; ++k) p += hl[k] * dr[k * 256 + t];
        red[t] = p;
        __syncthreads();
        for (int s = 128; s > 0; s >>= 1) {
            if (t < s) red[t] += red[t + s];
            __syncthreads();
        }
        if (t == 0) logits[cl] = red[0];
        __syncthreads();
    }

    if (t == 0) {
        float best = logits[0];
        int bi = 0;
        for (int cl = 1; cl < nclass; ++cl)
            if (logits[cl] > best) { best = logits[cl]; bi = cl; }
        sidx = bi;
        *idx_ptr = bi;
    }
    __syncthreads();

    if (enc != nullptr) {
        const float* er = enc + (size_t)sidx * H;
#pragma unroll
        for (int k = 0; k < 8; ++k) {
            int j = k * 256 + t;
            xv[j] = er[j];
        }
    }
}

__global__ __launch_bounds__(256) void final_kernel(
    const float* __restrict__ hv, const float* __restrict__ cv,
    const int* __restrict__ idx_ptr, float* __restrict__ out) {
    const int tid = blockIdx.x * 256 + threadIdx.x;
    const int col = tid & (H / 4 - 1);
    const float4 h4 = ((const float4*)hv)[col];
    const float4 c4 = ((const float4*)cv)[col];
    ((float4*)(out + B))[tid] = h4;
    ((float4*)(out + B + (size_t)B * H))[tid] = c4;
    if (tid < B) out[tid] = (float)(*idx_ptr);
}

extern "C" void kernel_launch(void* const* d_in, const int* in_sizes, int n_in,
                              void* d_out, int out_size, void* d_ws, size_t ws_size,
                              hipStream_t stream) {
    const float* W_ih      = (const float*)d_in[1];
    const float* W_hh      = (const float*)d_in[2];
    const float* b_ih      = (const float*)d_in[3];
    const float* b_hh      = (const float*)d_in[4];
    const float* enc_act   = (const float*)d_in[5];  // (NB-1, 4, H)
    const float* enc_block = (const float*)d_in[6];  // (NB-1, NB-1, H)
    const float* dec_act   = (const float*)d_in[7];  // (NB, 4, H)
    const float* dec_block = (const float*)d_in[8];  // (NB-1, NB-1, H)

    const bool use_bf16 =
        ws_size >= STATE_OFF_BYTES + (size_t)STATE_FLOATS * sizeof(float);

    uint4* Wih16 = (uint4*)d_ws;
    uint4* Whh16 = (uint4*)((char*)d_ws + WBF16_BYTES);
    float* state = use_bf16 ? (float*)((char*)d_ws + STATE_OFF_BYTES)
                            : (float*)d_ws;

    float* xv    = state;
    float* hv    = state + H;
    float* cv    = state + 2 * H;
    float* gates = state + 3 * H;
    int*   idxp  = (int*)(state + 7 * H);
    float* out = (float*)d_out;

    if (use_bf16) {
        convert_kernel<<<8192, 256, 0, stream>>>((const float4*)W_ih, Wih16);
        convert_kernel<<<8192, 256, 0, stream>>>((const float4*)W_hh, Whh16);
    }

    // block 0: x=h=c=0 -> gates = biases only
    zero_c_kernel<<<8, 256, 0, stream>>>(cv);
    bias_gates_kernel<<<32, 256, 0, stream>>>(b_ih, b_hh, gates);
    update_kernel<<<1, 256, 0, stream>>>(gates, xv, hv, cv,
                                         dec_act, 4, enc_act, idxp);

    for (int bid = 1; bid < NB; ++bid) {
        if (use_bf16)
            gates_bf16_kernel<<<2048, 256, 0, stream>>>(Wih16, Whh16, b_ih, b_hh,
                                                        xv, hv, gates);
        else
            gates_kernel<<<2048, 256, 0, stream>>>(W_ih, W_hh, b_ih, b_hh,
                                                   xv, hv, gates);
        update_kernel<<<1, 256, 0, stream>>>(
            gates, xv, hv, cv,
            dec_block + (size_t)(bid - 1) * (NB - 1) * H, bid,
            enc_block + (size_t)(bid - 1) * (NB - 1) * H, idxp);

        if (use_bf16)
            gates_bf16_kernel<<<2048, 256, 0, stream>>>(Wih16, Whh16, b_ih, b_hh,
                                                        xv, hv, gates);
        else
            gates_kernel<<<2048, 256, 0, stream>>>(W_ih, W_hh, b_ih, b_hh,
                                                   xv, hv, gates);
        update_kernel<<<1, 256, 0, stream>>>(
            gates, xv, hv, cv,
            dec_act + (size_t)bid * 4 * H, 4,
            (bid < NB - 1) ? (enc_act + (size_t)bid * 4 * H) : nullptr, idxp);
    }

    final_kernel<<<2048, 256, 0, stream>>>(hv, cv, idxp, out);
}

// Round 4
// 726.944 us; speedup vs baseline: 1.2968x; 1.0714x over previous
//
#include <hip/hip_runtime.h>
#include <math.h>
#include <stdint.h>

#define H 2048
#define B 1024
#define NB 12

// ws layout:
//   [0, 16MB)          : Wih int8 (8192 rows x 2048 bytes)
//   [16MB, 32MB)       : Whh int8
//   [32MB, +32KB)      : sih (8192 floats, per-row scale)
//   [.. , +32KB)       : shh
//   [.. ]              : fp32 state: x(H), h(H), c(H), gates(4H), idx(1)
#define WI8_BYTES (8192ull * 2048ull)             // 16 MB per matrix
#define SCALE_FLOATS 8192ull
#define STATE_FLOATS (7 * H + 1)
#define WS_NEED (2ull * WI8_BYTES + 2ull * SCALE_FLOATS * 4ull + (size_t)STATE_FLOATS * 4ull)

__global__ __launch_bounds__(256) void zero_c_kernel(float* __restrict__ cv) {
    int j = blockIdx.x * 256 + threadIdx.x;
    if (j < H) cv[j] = 0.f;
}

__global__ __launch_bounds__(256) void bias_gates_kernel(
    const float* __restrict__ bih, const float* __restrict__ bhh,
    float* __restrict__ gates) {
    int j = blockIdx.x * 256 + threadIdx.x;
    if (j < 4 * H) gates[j] = bih[j] + bhh[j];
}

// one wave per row: load 2048 fp32 -> wave absmax -> int8 quantize -> store
__global__ __launch_bounds__(256) void quant_kernel(
    const float* __restrict__ src, uint32_t* __restrict__ dst,
    float* __restrict__ scales) {
    const int wave = threadIdx.x >> 6;
    const int lane = threadIdx.x & 63;
    const int row = blockIdx.x * 4 + wave;

    const float4* __restrict__ s4 = (const float4*)(src + (size_t)row * H);
    float4 v[8];
    float m = 0.f;
#pragma unroll
    for (int k = 0; k < 8; ++k) {
        v[k] = s4[k * 64 + lane];
        m = fmaxf(m, fmaxf(fmaxf(fabsf(v[k].x), fabsf(v[k].y)),
                           fmaxf(fabsf(v[k].z), fabsf(v[k].w))));
    }
#pragma unroll
    for (int off = 32; off > 0; off >>= 1)
        m = fmaxf(m, __shfl_xor(m, off, 64));
    const float inv = (m > 0.f) ? 127.f / m : 0.f;

    uint32_t* __restrict__ drow = dst + (size_t)row * (H / 4);
#pragma unroll
    for (int k = 0; k < 8; ++k) {
        int qx = (int)rintf(v[k].x * inv);
        int qy = (int)rintf(v[k].y * inv);
        int qz = (int)rintf(v[k].z * inv);
        int qw = (int)rintf(v[k].w * inv);
        drow[k * 64 + lane] = (uint32_t)(qx & 0xff) |
                              ((uint32_t)(qy & 0xff) << 8) |
                              ((uint32_t)(qz & 0xff) << 16) |
                              ((uint32_t)(qw & 0xff) << 24);
    }
    if (lane == 0) scales[row] = (m > 0.f) ? m / 127.f : 0.f;
}

__device__ __forceinline__ float dot4_i8(uint32_t w, float4 v) {
    return (float)((int)(w << 24) >> 24) * v.x +
           (float)((int)(w << 16) >> 24) * v.y +
           (float)((int)(w << 8) >> 24) * v.z +
           (float)((int)w >> 24) * v.w;
}

// int8 matvec, XCD-sliced for L2 residency:
//   blockIdx % 8 selects the XCD (dispatch round-robin heuristic); each XCD
//   owns a fixed 1024-row slice of Wih + Whh (2+2 MB = its 4 MiB L2).
//   4 rows per wave (amortizes x/h broadcast loads 4x). 512 blocks x 256.
__global__ __launch_bounds__(256) void gates_i8_kernel(
    const uint4* __restrict__ Wih, const uint4* __restrict__ Whh,
    const float* __restrict__ sih, const float* __restrict__ shh,
    const float* __restrict__ bih, const float* __restrict__ bhh,
    const float* __restrict__ x, const float* __restrict__ h,
    float* __restrict__ gates) {
    const int wave = threadIdx.x >> 6;
    const int lane = threadIdx.x & 63;
    const int xcd = blockIdx.x & 7;
    const int blk = blockIdx.x >> 3;            // 0..63
    const int row0 = xcd * 1024 + blk * 16 + wave * 4;

    const float4* __restrict__ x4 = (const float4*)x;
    const float4* __restrict__ h4 = (const float4*)h;

    float ai[4] = {0.f, 0.f, 0.f, 0.f};
    float ah[4] = {0.f, 0.f, 0.f, 0.f};
#pragma unroll
    for (int k = 0; k < 2; ++k) {
        const int j = k * 64 + lane;            // uint4 col index, row=128 uint4
        float4 xa = x4[4 * j + 0], xb = x4[4 * j + 1];
        float4 xc = x4[4 * j + 2], xd = x4[4 * j + 3];
#pragma unroll
        for (int r = 0; r < 4; ++r) {
            uint4 w = Wih[(size_t)(row0 + r) * 128 + j];
            ai[r] += dot4_i8(w.x, xa) + dot4_i8(w.y, xb) +
                     dot4_i8(w.z, xc) + dot4_i8(w.w, xd);
        }
        float4 ha = h4[4 * j + 0], hb = h4[4 * j + 1];
        float4 hc = h4[4 * j + 2], hd = h4[4 * j + 3];
#pragma unroll
        for (int r = 0; r < 4; ++r) {
            uint4 w = Whh[(size_t)(row0 + r) * 128 + j];
            ah[r] += dot4_i8(w.x, ha) + dot4_i8(w.y, hb) +
                     dot4_i8(w.z, hc) + dot4_i8(w.w, hd);
        }
    }
#pragma unroll
    for (int off = 32; off > 0; off >>= 1) {
#pragma unroll
        for (int r = 0; r < 4; ++r) {
            ai[r] += __shfl_down(ai[r], off, 64);
            ah[r] += __shfl_down(ah[r], off, 64);
        }
    }
    if (lane == 0) {
#pragma unroll
        for (int r = 0; r < 4; ++r) {
            const int row = row0 + r;
            gates[row] = ai[r] * sih[row] + ah[r] * shh[row] +
                         bih[row] + bhh[row];
        }
    }
}

// fp32 matvec (exact path for the last LSTM steps + fallback)
__global__ __launch_bounds__(256) void gates_kernel(
    const float* __restrict__ Wih, const float* __restrict__ Whh,
    const float* __restrict__ bih, const float* __restrict__ bhh,
    const float* __restrict__ x, const float* __restrict__ h,
    float* __restrict__ gates) {
    const int wave = threadIdx.x >> 6;
    const int lane = threadIdx.x & 63;
    const int row = blockIdx.x * 4 + wave;

    const float4* __restrict__ Wi4 = (const float4*)(Wih + (size_t)row * H);
    const float4* __restrict__ Wh4 = (const float4*)(Whh + (size_t)row * H);
    const float4* __restrict__ x4 = (const float4*)x;
    const float4* __restrict__ h4 = (const float4*)h;

    float acc = 0.f;
#pragma unroll
    for (int k = 0; k < H / 256; ++k) {
        int j = k * 64 + lane;
        float4 w = Wi4[j];
        float4 v = x4[j];
        acc += w.x * v.x + w.y * v.y + w.z * v.z + w.w * v.w;
    }
#pragma unroll
    for (int k = 0; k < H / 256; ++k) {
        int j = k * 64 + lane;
        float4 w = Wh4[j];
        float4 v = h4[j];
        acc += w.x * v.x + w.y * v.y + w.z * v.z + w.w * v.w;
    }
    for (int off = 32; off > 0; off >>= 1) acc += __shfl_down(acc, off, 64);
    if (lane == 0) gates[row] = acc + bih[row] + bhh[row];
}

// single-block: h,c update; logits = h @ dec[0:nclass].T; argmax; gather x=enc[idx]
__global__ __launch_bounds__(256) void update_kernel(
    const float* __restrict__ gates,
    float* __restrict__ xv, float* __restrict__ hv, float* __restrict__ cv,
    const float* __restrict__ dec, int nclass,
    const float* __restrict__ enc, int* __restrict__ idx_ptr) {
    const int t = threadIdx.x;
    __shared__ float red[256];
    __shared__ float logits[16];
    __shared__ int sidx;

    float hl[8];
#pragma unroll
    for (int k = 0; k < 8; ++k) {
        int j = k * 256 + t;
        float ig = gates[j];
        float fg = gates[H + j];
        float gg = gates[2 * H + j];
        float og = gates[3 * H + j];
        float si = 1.f / (1.f + expf(-ig));
        float sf = 1.f / (1.f + expf(-fg));
        float so = 1.f / (1.f + expf(-og));
        float tg = tanhf(gg);
        float c2 = sf * cv[j] + si * tg;
        float h2 = so * tanhf(c2);
        cv[j] = c2;
        hv[j] = h2;
        hl[k] = h2;
    }
    __syncthreads();

    for (int cl = 0; cl < nclass; ++cl) {
        const float* dr = dec + (size_t)cl * H;
        float p = 0.f;
#pragma unroll
        for (int k = 0; k < 8; ++k) p += hl[k] * dr[k * 256 + t];
        red[t] = p;
        __syncthreads();
        for (int s = 128; s > 0; s >>= 1) {
            if (t < s) red[t] += red[t + s];
            __syncthreads();
        }
        if (t == 0) logits[cl] = red[0];
        __syncthreads();
    }

    if (t == 0) {
        float best = logits[0];
        int bi = 0;
        for (int cl = 1; cl < nclass; ++cl)
            if (logits[cl] > best) { best = logits[cl]; bi = cl; }
        sidx = bi;
        *idx_ptr = bi;
    }
    __syncthreads();

    if (enc != nullptr) {
        const float* er = enc + (size_t)sidx * H;
#pragma unroll
        for (int k = 0; k < 8; ++k) {
            int j = k * 256 + t;
            xv[j] = er[j];
        }
    }
}

__global__ __launch_bounds__(256) void final_kernel(
    const float* __restrict__ hv, const float* __restrict__ cv,
    const int* __restrict__ idx_ptr, float* __restrict__ out) {
    const int tid = blockIdx.x * 256 + threadIdx.x;
    const int col = tid & (H / 4 - 1);
    const float4 h4 = ((const float4*)hv)[col];
    const float4 c4 = ((const float4*)cv)[col];
    ((float4*)(out + B))[tid] = h4;
    ((float4*)(out + B + (size_t)B * H))[tid] = c4;
    if (tid < B) out[tid] = (float)(*idx_ptr);
}

extern "C" void kernel_launch(void* const* d_in, const int* in_sizes, int n_in,
                              void* d_out, int out_size, void* d_ws, size_t ws_size,
                              hipStream_t stream) {
    const float* W_ih      = (const float*)d_in[1];
    const float* W_hh      = (const float*)d_in[2];
    const float* b_ih      = (const float*)d_in[3];
    const float* b_hh      = (const float*)d_in[4];
    const float* enc_act   = (const float*)d_in[5];  // (NB-1, 4, H)
    const float* enc_block = (const float*)d_in[6];  // (NB-1, NB-1, H)
    const float* dec_act   = (const float*)d_in[7];  // (NB, 4, H)
    const float* dec_block = (const float*)d_in[8];  // (NB-1, NB-1, H)

    const bool use_i8 = ws_size >= WS_NEED;
    // last FP32_TAIL gates calls run in fp32: int8 noise in c decays ~0.5/step
    const int FP32_TAIL = 3;
    const int NGATES = 2 * (NB - 1);  // 22

    uint32_t* Wih8 = (uint32_t*)d_ws;
    uint32_t* Whh8 = (uint32_t*)((char*)d_ws + WI8_BYTES);
    float* sih = (float*)((char*)d_ws + 2 * WI8_BYTES);
    float* shh = sih + SCALE_FLOATS;
    float* state = use_i8 ? (shh + SCALE_FLOATS) : (float*)d_ws;

    float* xv    = state;
    float* hv    = state + H;
    float* cv    = state + 2 * H;
    float* gates = state + 3 * H;
    int*   idxp  = (int*)(state + 7 * H);
    float* out = (float*)d_out;

    if (use_i8) {
        quant_kernel<<<2048, 256, 0, stream>>>(W_ih, Wih8, sih);
        quant_kernel<<<2048, 256, 0, stream>>>(W_hh, Whh8, shh);
    }

    // block 0: x=h=c=0 -> gates = biases only
    zero_c_kernel<<<8, 256, 0, stream>>>(cv);
    bias_gates_kernel<<<32, 256, 0, stream>>>(b_ih, b_hh, gates);
    update_kernel<<<1, 256, 0, stream>>>(gates, xv, hv, cv,
                                         dec_act, 4, enc_act, idxp);

    int g = 0;  // gates-call counter
    for (int bid = 1; bid < NB; ++bid) {
        if (use_i8 && g < NGATES - FP32_TAIL)
            gates_i8_kernel<<<512, 256, 0, stream>>>(
                (const uint4*)Wih8, (const uint4*)Whh8, sih, shh,
                b_ih, b_hh, xv, hv, gates);
        else
            gates_kernel<<<2048, 256, 0, stream>>>(W_ih, W_hh, b_ih, b_hh,
                                                   xv, hv, gates);
        ++g;
        update_kernel<<<1, 256, 0, stream>>>(
            gates, xv, hv, cv,
            dec_block + (size_t)(bid - 1) * (NB - 1) * H, bid,
            enc_block + (size_t)(bid - 1) * (NB - 1) * H, idxp);

        if (use_i8 && g < NGATES - FP32_TAIL)
            gates_i8_kernel<<<512, 256, 0, stream>>>(
                (const uint4*)Wih8, (const uint4*)Whh8, sih, shh,
                b_ih, b_hh, xv, hv, gates);
        else
            gates_kernel<<<2048, 256, 0, stream>>>(W_ih, W_hh, b_ih, b_hh,
                                                   xv, hv, gates);
        ++g;
        update_kernel<<<1, 256, 0, stream>>>(
            gates, xv, hv, cv,
            dec_act + (size_t)bid * 4 * H, 4,
            (bid < NB - 1) ? (enc_act + (size_t)bid * 4 * H) : nullptr, idxp);
    }

    final_kernel<<<2048, 256, 0, stream>>>(hv, cv, idxp, out);
}